// Round 5
// baseline (35.091 us; speedup 1.0000x reference)
//
#include <hip/hip_runtime.h>

// NonLinearConv2d: unfold(3x3,pad1) -> sum_k f((v_k - theta_kc)/D) with
// f(a) = softplus(a)^2 - softplus(a-DLT)^2, then BatchNorm2d (training,
// biased stats) per channel.
//
// Round 5: TWO kernels (was three). nlc_compute unchanged from round 4
// (factored exponential: 2 v_log + 5 VALU per term). nlc_finish fuses the
// stats reduction (block-redundant, 8 blocks per channel reduce the same 512
// L2-resident partials) with the BN apply; payload loads issued before the
// reduction to hide latency. Tests the launch-overhead hypothesis.

constexpr float INV_D  = 13.333333333333334f;   // 1/(2*n*VT) = 1/0.075
constexpr float C_NEG  = 0.2635971381157267f;   // e^-(V_D/DENOM) = e^-4/3
// V = acc * OUT_SC;  OUT_SC = ALPHA * R_TIA * ln(2)^2
constexpr double OUT_SC = 5.625e-5 * 0.48045301391820142;
constexpr int   NCHUNK = 512;                   // 32768 pixels / 64

// ---------------------------------------------------------------------------
// Kernel 1: raw acc (into d_out) + per-(channel,chunk) partial sum / sumsq.
// Grid: 2048 = 512 pixel-chunks x 4 channel-groups; block 256 = 4 waves;
// wave handles 64 consecutive pixels x 4 channels.  (unchanged from round 4)
// ---------------------------------------------------------------------------
__global__ __launch_bounds__(256, 4)
void nlc_compute(const float* __restrict__ x, const float* __restrict__ theta,
                 float* __restrict__ vout, float* __restrict__ psum,
                 float* __restrict__ psq)
{
    __shared__ alignas(16) float thc[27 * 16];  // e^{-theta*INV_D}, 16 ch
    const int tid   = threadIdx.x;
    const int chunk = blockIdx.x >> 2;
    const int cbase = (blockIdx.x & 3) * 16;

    for (int i = tid; i < 27 * 16; i += 256) {
        const int k = i >> 4, cc = i & 15;
        thc[i] = __expf(-theta[k * 64 + cbase + cc] * INV_D);
    }
    __syncthreads();

    const int lane = tid & 63;
    const int wv   = tid >> 6;
    const int p    = chunk * 64 + lane;   // global pixel id
    const int n    = p >> 10;
    const int hw   = p & 1023;
    const int h    = hw >> 5;
    const int w    = hw & 31;

    // e^{v_k * INV_D} for the 27 patch values (channel-major then ki,kj =
    // unfold order); zero-padded borders give e^0 = 1.
    float Ev[27];
    const float* xn = x + n * 3072;
#pragma unroll
    for (int ci = 0; ci < 3; ++ci) {
#pragma unroll
        for (int ki = 0; ki < 3; ++ki) {
#pragma unroll
            for (int kj = 0; kj < 3; ++kj) {
                const int hh = h + ki - 1;
                const int ww = w + kj - 1;
                float val = 0.f;
                if (hh >= 0 && hh < 32 && ww >= 0 && ww < 32)
                    val = xn[ci * 1024 + hh * 32 + ww];
                Ev[ci * 9 + ki * 3 + kj] =
                    fminf(__expf(val * INV_D), 3.0e38f);
            }
        }
    }

    const float4* thv4 = reinterpret_cast<const float4*>(thc);
    float acc[4] = {0.f, 0.f, 0.f, 0.f};

#pragma unroll
    for (int k = 0; k < 27; ++k) {
        const float4 t4 = thv4[k * 4 + wv];   // wave-uniform b128 broadcast
        const float tho[4] = {t4.x, t4.y, t4.z, t4.w};
#pragma unroll
        for (int i = 0; i < 4; ++i) {
            const float E  = Ev[k] * tho[i];                // e^{(v-th)/D}
            const float q1 = 1.0f + E;
            const float q2 = fmaf(E, C_NEG, 1.0f);
            const float l1 = __log2f(q1);                   // sp(a)*log2e
            const float l2 = __log2f(q2);                   // sp(a-DLT)*log2e
            acc[i] = fmaf(l1, l1, acc[i]);
            acc[i] = fmaf(-l2, l2, acc[i]);
        }
    }

#pragma unroll
    for (int i = 0; i < 4; ++i) {
        const int   c  = cbase + wv * 4 + i;
        const float vo = acc[i];                 // raw (unscaled) accumulator
        vout[(n << 16) + (c << 10) + hw] = vo;   // NCHW, coalesced per wave

        float s = vo, q = vo * vo;
#pragma unroll
        for (int off = 32; off > 0; off >>= 1) {
            s += __shfl_xor(s, off, 64);
            q += __shfl_xor(q, off, 64);
        }
        if (lane == 0) {
            psum[c * NCHUNK + chunk] = s;    // [channel][chunk] layout
            psq [c * NCHUNK + chunk] = q;
        }
    }
}

// ---------------------------------------------------------------------------
// Kernel 2: fused stats + BN apply. Grid: 512 blocks = 64 channels x 8
// segments; each block redundantly reduces its channel's 512 partials
// (deterministic double tree), then normalizes 4 full (n,c) planes in-place.
// Payload loads are issued before the reduction to hide HBM latency.
// ---------------------------------------------------------------------------
__global__ __launch_bounds__(256)
void nlc_finish(const float* __restrict__ psum, const float* __restrict__ psq,
                const float* __restrict__ gamma, const float* __restrict__ beta,
                float* __restrict__ vout)
{
    const int b   = blockIdx.x;
    const int c   = b >> 3;        // channel
    const int seg = b & 7;         // 4-plane segment within the channel
    const int tid = threadIdx.x;

    // issue payload loads early (independent of the stats)
    float4* p0 = reinterpret_cast<float4*>(vout) + (seg * 4 + 0) * 16384 + c * 256 + tid;
    float4* p1 = p0 + 16384;
    float4* p2 = p1 + 16384;
    float4* p3 = p2 + 16384;
    float4 v0 = *p0, v1 = *p1, v2 = *p2, v3 = *p3;

    // block-redundant reduction of channel c's 512 partials (L2-resident)
    double s = (double)psum[c * NCHUNK + tid] + (double)psum[c * NCHUNK + 256 + tid];
    double q = (double)psq [c * NCHUNK + tid] + (double)psq [c * NCHUNK + 256 + tid];
#pragma unroll
    for (int off = 32; off > 0; off >>= 1) {
        s += __shfl_xor(s, off, 64);
        q += __shfl_xor(q, off, 64);
    }
    __shared__ double ls[4], lq[4];
    __shared__ float  scsh[2];
    if ((tid & 63) == 0) { ls[tid >> 6] = s; lq[tid >> 6] = q; }
    __syncthreads();
    if (tid == 0) {
        s = ls[0] + ls[1] + ls[2] + ls[3];
        q = lq[0] + lq[1] + lq[2] + lq[3];
        const double inv    = 1.0 / 32768.0;
        const double mean_a = s * inv;                       // acc units
        const double var_a  = q * inv - mean_a * mean_a;     // biased
        const double var_V  = var_a * OUT_SC * OUT_SC;
        const double rstd   = 1.0 / sqrt(var_V + 1e-5);
        const double sc     = (double)gamma[c] * rstd * OUT_SC;  // per acc
        const double sh     = (double)beta[c] - mean_a * sc;
        scsh[0] = (float)sc;
        scsh[1] = (float)sh;
    }
    __syncthreads();
    const float sc = scsh[0];
    const float sh = scsh[1];

#define NLC_BN4(v) \
    v.x = fmaf(v.x, sc, sh); v.y = fmaf(v.y, sc, sh); \
    v.z = fmaf(v.z, sc, sh); v.w = fmaf(v.w, sc, sh);
    NLC_BN4(v0) NLC_BN4(v1) NLC_BN4(v2) NLC_BN4(v3)
#undef NLC_BN4

    *p0 = v0; *p1 = v1; *p2 = v2; *p3 = v3;
}

extern "C" void kernel_launch(void* const* d_in, const int* in_sizes, int n_in,
                              void* d_out, int out_size, void* d_ws, size_t ws_size,
                              hipStream_t stream)
{
    const float* x     = (const float*)d_in[0];
    const float* theta = (const float*)d_in[1];
    const float* gamma = (const float*)d_in[2];
    const float* beta  = (const float*)d_in[3];
    float* out = (float*)d_out;

    float* psum = (float*)d_ws;                 // 64*512 floats
    float* psq  = psum + 64 * NCHUNK;           // 64*512 floats

    nlc_compute<<<NCHUNK * 4, 256, 0, stream>>>(x, theta, out, psum, psq);
    nlc_finish <<<512, 256, 0, stream>>>(psum, psq, gamma, beta, out);
}